// Round 2
// baseline (88.209 us; speedup 1.0000x reference)
//
#include <hip/hip_runtime.h>

#define SEQ 1024

typedef __attribute__((ext_vector_type(2))) float f2;

// Closed-form qlayer for one token row y[0..7]:
// angles a = {y0+t0, y1+t1, y2+y3+t2, t3, y4+t4, y5+t5, y6+t6, y7+t7}
// c_w = cos(a_w); out[0] = c1..c7, out[w] = c0..cw (w>=1).
static __device__ __forceinline__ void qrow(const float th[8], const float y[8], float o[8]) {
    float a[8];
    a[0] = y[0] + th[0];
    a[1] = y[1] + th[1];
    a[2] = y[2] + y[3] + th[2];
    a[3] = th[3];
    a[4] = y[4] + th[4];
    a[5] = y[5] + th[5];
    a[6] = y[6] + th[6];
    a[7] = y[7] + th[7];
    float c[8];
#pragma unroll
    for (int w = 0; w < 8; ++w) c[w] = __cosf(a[w]);
    o[1] = c[0] * c[1];
#pragma unroll
    for (int w = 2; w < 8; ++w) o[w] = o[w - 1] * c[w];
    float s = c[7];
#pragma unroll
    for (int w = 6; w >= 1; --w) s *= c[w];
    o[0] = s;
}

// ---- Kernel A: h = qlayer(x) for all 16*1024 tokens, written ONCE to d_ws.
// Replaces the per-block replicated stage-1 (512 copies of the same work).
__global__ __launch_bounds__(256) void qlayer_front(const float* __restrict__ x,
                                                    const float* __restrict__ theta,
                                                    float* __restrict__ h) {
    const int r = (blockIdx.x << 8) + threadIdx.x;  // token row 0..16383
    float th[8];
#pragma unroll
    for (int w = 0; w < 8; ++w) th[w] = theta[w];
    const float4 va = ((const float4*)x)[2 * r];
    const float4 vb = ((const float4*)x)[2 * r + 1];
    const float y[8] = {va.x, va.y, va.z, va.w, vb.x, vb.y, vb.z, vb.w};
    float o[8];
    qrow(th, y, o);
    ((float4*)h)[2 * r]     = make_float4(o[0], o[1], o[2], o[3]);
    ((float4*)h)[2 * r + 1] = make_float4(o[4], o[5], o[6], o[7]);
}

// ---- Kernel B: 2-head attention (dk=4) over h (read from L2) + final qlayer.
// Grid: 1024 blocks (16 batches x 64 query-tiles of 16), 256 threads.
// No h-staging in LDS: h is 512 KB total, L2-resident; a wave-load presents
// only 8 distinct 32B rows (8-lane broadcast groups) -> coalescer merges.
// Per-thread state ~85 VGPRs (Qr=2) -> 5-6 waves/SIMD achievable; LDS 2.6 KB.
// Lane layout: wv = key quarter (256 k), g = lane>>3 query pair, m = lane&7
// covers 32 contiguous keys. Partial reduction: shfl-xor over m (3 steps),
// then one 80B dump per 8-lane group (bank-conflict-free: 20g mod 32 distinct).
__global__ __launch_bounds__(256, 4) void mhaq_attn(const float* __restrict__ h,
                                                    const float* __restrict__ theta,
                                                    float* __restrict__ out) {
    __shared__ __align__(16) float part[640];  // [wv][g][qq*10+j] = 4*8*20

    const int b   = blockIdx.x >> 6;         // batch
    const int qof = (blockIdx.x & 63) << 4;  // first query of this block's 16
    const int t   = threadIdx.x;
    const int lane = t & 63;
    const int wv   = t >> 6;      // key quarter 0..3 (256 keys each)
    const int g    = lane >> 3;   // query-pair group 0..7
    const int m    = lane & 7;    // 32-key sub-chunk 0..7
    const int q0   = qof + (g << 1);

    float th[8];
#pragma unroll
    for (int w = 0; w < 8; ++w) th[w] = theta[w];

    const float4* hb = (const float4*)(h + (size_t)b * SEQ * 8);

    const float qscale = 0.5f * 1.44269504f;  // 1/sqrt(dk) * log2(e)
    f2 qv[2][4];
#pragma unroll
    for (int qq = 0; qq < 2; ++qq) {
        const float4 qa = hb[2 * (q0 + qq)];      // broadcast within group
        const float4 qb = hb[2 * (q0 + qq) + 1];
        qv[qq][0] = f2{qa.x, qa.y} * qscale;
        qv[qq][1] = f2{qa.z, qa.w} * qscale;
        qv[qq][2] = f2{qb.x, qb.y} * qscale;
        qv[qq][3] = f2{qb.z, qb.w} * qscale;
    }

    float l0[2] = {0.f, 0.f};
    float l1[2] = {0.f, 0.f};
    f2 a01[2], a23[2], a45[2], a67[2];
#pragma unroll
    for (int qq = 0; qq < 2; ++qq) {
        a01[qq] = f2{0.f, 0.f};
        a23[qq] = f2{0.f, 0.f};
        a45[qq] = f2{0.f, 0.f};
        a67[qq] = f2{0.f, 0.f};
    }

    const int kbase = (wv << 8) + (m << 5);  // this lane's 32-key chunk
#pragma unroll 4
    for (int i = 0; i < 32; ++i) {
        const float4 k0 = hb[2 * (kbase + i)];
        const float4 k1 = hb[2 * (kbase + i) + 1];
        const f2 k01 = {k0.x, k0.y}, k23 = {k0.z, k0.w};
        const f2 k45 = {k1.x, k1.y}, k67 = {k1.z, k1.w};
#pragma unroll
        for (int qq = 0; qq < 2; ++qq) {
            const f2 d0 = qv[qq][0] * k01 + qv[qq][1] * k23;
            const f2 d1 = qv[qq][2] * k45 + qv[qq][3] * k67;
            const float e0 = __builtin_amdgcn_exp2f(d0.x + d0.y);
            const float e1 = __builtin_amdgcn_exp2f(d1.x + d1.y);
            l0[qq] += e0;
            l1[qq] += e1;
            const f2 e0v = {e0, e0}, e1v = {e1, e1};
            a01[qq] += e0v * k01;
            a23[qq] += e0v * k23;
            a45[qq] += e1v * k45;
            a67[qq] += e1v * k67;
        }
    }

    // ---- reduce over m (8 lanes per group) via shfl-xor butterfly ----
    float buf[20];
#pragma unroll
    for (int qq = 0; qq < 2; ++qq) {
        buf[qq * 10 + 0] = l0[qq];
        buf[qq * 10 + 1] = l1[qq];
        buf[qq * 10 + 2] = a01[qq].x;
        buf[qq * 10 + 3] = a01[qq].y;
        buf[qq * 10 + 4] = a23[qq].x;
        buf[qq * 10 + 5] = a23[qq].y;
        buf[qq * 10 + 6] = a45[qq].x;
        buf[qq * 10 + 7] = a45[qq].y;
        buf[qq * 10 + 8] = a67[qq].x;
        buf[qq * 10 + 9] = a67[qq].y;
    }
#pragma unroll
    for (int d = 1; d <= 4; d <<= 1)
#pragma unroll
        for (int i = 0; i < 20; ++i) buf[i] += __shfl_xor(buf[i], d, 64);

    if (m == 0) {
        // 8 writers/wave at word offsets 20g: 20g mod 32 all distinct ->
        // the 8 float4 stores partition the 32 banks, conflict-free.
        float4* pp = (float4*)&part[((wv << 3) + g) * 20];
#pragma unroll
        for (int i = 0; i < 5; ++i) pp[i] = ((const float4*)buf)[i];
    }
    __syncthreads();

    // ---- epilogue: thread q < 16 combines 4 quarters + finalizes ----
    if (t < 16) {
        const int g2 = t >> 1, qq = t & 1;
        float r[10];
#pragma unroll
        for (int j = 0; j < 10; ++j) {
            float s = 0.f;
#pragma unroll
            for (int w = 0; w < 4; ++w)
                s += part[((w << 3) + g2) * 20 + qq * 10 + j];
            r[j] = s;
        }
        const float inv0 = 1.0f / r[0];
        const float inv1 = 1.0f / r[1];
        const float y[8] = {r[2] * inv0, r[3] * inv0, r[4] * inv0, r[5] * inv0,
                            r[6] * inv1, r[7] * inv1, r[8] * inv1, r[9] * inv1};
        float o[8];
        qrow(th, y, o);
        float4* op = (float4*)(out + ((size_t)(b * SEQ + qof + t)) * 8);
        op[0] = make_float4(o[0], o[1], o[2], o[3]);
        op[1] = make_float4(o[4], o[5], o[6], o[7]);
    }
}

extern "C" void kernel_launch(void* const* d_in, const int* in_sizes, int n_in,
                              void* d_out, int out_size, void* d_ws, size_t ws_size,
                              hipStream_t stream) {
    const float* x     = (const float*)d_in[0];
    const float* theta = (const float*)d_in[1];
    float* out         = (float*)d_out;
    float* h           = (float*)d_ws;  // 16*1024*8 floats = 512 KB
    qlayer_front<<<dim3(64), dim3(256), 0, stream>>>(x, theta, h);
    mhaq_attn<<<dim3(1024), dim3(256), 0, stream>>>(h, theta, out);
}

// Round 3
// 70.184 us; speedup vs baseline: 1.2568x; 1.2568x over previous
//
#include <hip/hip_runtime.h>

#define SEQ 1024

// h storage: row k = two 16B slots s=2k, 2k+1; physical slot P(s) = s ^ ((s>>5)&7)
// (word addr 4*P). Bijective (bits 0..2 XORed with untouched bits 5..7).
// Bank-cluster (4-bank group) = P&7:
//  - stage-2 key read: s = wv*512 + m*32 + 2i -> cluster (2i&7)^(m&7); per
//    wave-read (i,wv fixed) m&7 spans all 8 clusters, 2 slots each -> 2-way, free.
//  - stage-0 store: 64 lanes spread evenly over all 8 clusters (bandwidth-min).
//  - q-loads: per-group broadcast (4 distinct slots/wave).
static __device__ __forceinline__ int slot_addr(int s) {
    return (s ^ ((s >> 5) & 7)) << 2;
}

// Closed-form qlayer for one token row y[0..7]:
// angles a = {y0+t0, y1+t1, y2+y3+t2, t3, y4+t4, y5+t5, y6+t6, y7+t7}
// c_w = cos(a_w); out[0] = c1..c7, out[w] = c0..cw (w>=1).
static __device__ __forceinline__ void qrow(const float th[8], const float y[8], float o[8]) {
    float a[8];
    a[0] = y[0] + th[0];
    a[1] = y[1] + th[1];
    a[2] = y[2] + y[3] + th[2];
    a[3] = th[3];
    a[4] = y[4] + th[4];
    a[5] = y[5] + th[5];
    a[6] = y[6] + th[6];
    a[7] = y[7] + th[7];
    float c[8];
#pragma unroll
    for (int w = 0; w < 8; ++w) c[w] = __cosf(a[w]);
    o[1] = c[0] * c[1];
#pragma unroll
    for (int w = 2; w < 8; ++w) o[w] = o[w - 1] * c[w];
    float s = c[7];
#pragma unroll
    for (int w = 6; w >= 1; --w) s *= c[w];
    o[0] = s;
}

// Fused qlayer -> 2-head attention (dk=4) -> qlayer.
// v4 (clean occupancy test): 1024 blocks (16 batches x 64 tiles of 16 q),
// 256 threads, 37 KB LDS -> 4 blocks/CU resident = 16 waves/CU (4/SIMD,
// 2x R0). Keys stay in LDS (R2 lesson). Wave wv = key quarter (256 k);
// lane: g = query group (4 q, registers), m = 16-key chunk (16 iters).
// Reduction: in-register shfl_xor butterfly over m bits 0..2 (3 steps),
// lanes m%8==0 dump 40 floats -> 128 rows x 40 words LDS, 16 threads combine.
__global__ __launch_bounds__(256, 4) void mhaq_fused(const float* __restrict__ x,
                                                     const float* __restrict__ theta,
                                                     float* __restrict__ out) {
    __shared__ __align__(16) float smem[8192 + 1280];
    float* const part = smem + 8192;

    const int b   = blockIdx.x >> 6;         // batch
    const int qof = (blockIdx.x & 63) << 4;  // first query of this block's 16
    const int t   = threadIdx.x;

    float th[8];
#pragma unroll
    for (int w = 0; w < 8; ++w) th[w] = theta[w];

    // ---- Stage 0: h[b] (1024 x 8) into LDS (recompute; ~0.8us/SIMD,
    // cheaper than a separate front kernel + launch gap per R2 evidence) ----
    const float4* xb = (const float4*)(x + (size_t)b * SEQ * 8);
    float4 v0[4], v1[4];
#pragma unroll
    for (int r = 0; r < 4; ++r) {
        const int k = t + (r << 8);
        v0[r] = xb[2 * k];
        v1[r] = xb[2 * k + 1];
    }
#pragma unroll
    for (int r = 0; r < 4; ++r) {
        const int k = t + (r << 8);
        const float y[8] = {v0[r].x, v0[r].y, v0[r].z, v0[r].w,
                            v1[r].x, v1[r].y, v1[r].z, v1[r].w};
        float o[8];
        qrow(th, y, o);
        *(float4*)&smem[slot_addr(2 * k)]     = make_float4(o[0], o[1], o[2], o[3]);
        *(float4*)&smem[slot_addr(2 * k + 1)] = make_float4(o[4], o[5], o[6], o[7]);
    }
    __syncthreads();

    // ---- Stage 2: attention inner loop ----
    const int lane = t & 63;
    const int wv   = t >> 6;      // key quarter 0..3 (256 keys each)
    const int g    = lane >> 4;   // query group 0..3 (4 q each)
    const int m    = lane & 15;   // 16-key sub-chunk 0..15
    const int q0   = qof + (g << 2);

    const float qscale = 0.5f * 1.44269504f;  // 1/sqrt(dk) * log2(e)
    float qv[4][8];
#pragma unroll
    for (int qq = 0; qq < 4; ++qq) {
        const float4 qa = *(const float4*)&smem[slot_addr(2 * (q0 + qq))];      // broadcast
        const float4 qb = *(const float4*)&smem[slot_addr(2 * (q0 + qq) + 1)];  // broadcast
        qv[qq][0] = qa.x * qscale; qv[qq][1] = qa.y * qscale;
        qv[qq][2] = qa.z * qscale; qv[qq][3] = qa.w * qscale;
        qv[qq][4] = qb.x * qscale; qv[qq][5] = qb.y * qscale;
        qv[qq][6] = qb.z * qscale; qv[qq][7] = qb.w * qscale;
    }

    // acc[qq] = {l0, l1, a0..a3 (head0), a4..a7 (head1)}
    float acc[4][10];
#pragma unroll
    for (int qq = 0; qq < 4; ++qq)
#pragma unroll
        for (int j = 0; j < 10; ++j) acc[qq][j] = 0.f;

    const int sbase = (wv << 9) + (m << 5);  // slot of this lane's first key
#pragma unroll 4
    for (int i = 0; i < 16; ++i) {
        const int s0 = sbase + (i << 1);
        const float4 k0 = *(const float4*)&smem[slot_addr(s0)];
        const float4 k1 = *(const float4*)&smem[slot_addr(s0 + 1)];
#pragma unroll
        for (int qq = 0; qq < 4; ++qq) {
            const float d0 = fmaf(qv[qq][0], k0.x, fmaf(qv[qq][1], k0.y,
                             fmaf(qv[qq][2], k0.z, qv[qq][3] * k0.w)));
            const float d1 = fmaf(qv[qq][4], k1.x, fmaf(qv[qq][5], k1.y,
                             fmaf(qv[qq][6], k1.z, qv[qq][7] * k1.w)));
            const float e0 = __builtin_amdgcn_exp2f(d0);
            const float e1 = __builtin_amdgcn_exp2f(d1);
            acc[qq][0] += e0;
            acc[qq][1] += e1;
            acc[qq][2] = fmaf(e0, k0.x, acc[qq][2]);
            acc[qq][3] = fmaf(e0, k0.y, acc[qq][3]);
            acc[qq][4] = fmaf(e0, k0.z, acc[qq][4]);
            acc[qq][5] = fmaf(e0, k0.w, acc[qq][5]);
            acc[qq][6] = fmaf(e1, k1.x, acc[qq][6]);
            acc[qq][7] = fmaf(e1, k1.y, acc[qq][7]);
            acc[qq][8] = fmaf(e1, k1.z, acc[qq][8]);
            acc[qq][9] = fmaf(e1, k1.w, acc[qq][9]);
        }
    }

    // ---- in-register butterfly over m bits 0..2 (lanes m, m^1, m^2, m^4) ----
    float* const accf = &acc[0][0];
#pragma unroll
    for (int j = 0; j < 40; ++j) {
        float v = accf[j];
        v += __shfl_xor(v, 1, 64);
        v += __shfl_xor(v, 2, 64);
        v += __shfl_xor(v, 4, 64);
        accf[j] = v;
    }

    // ---- dump: lanes m in {0,8}: 8 rows/wave, 128 rows x 40 words total ----
    // word offset rid*40: per float4 #i cluster (10*rid+i)&7, rid consecutive
    // -> 4 clusters x 2 lanes = 2-way, free.
    if ((m & 7) == 0) {
        const int rid = (((wv << 2) + g) << 1) + (m >> 3);
        float4* pp = (float4*)&part[rid * 40];
#pragma unroll
        for (int i = 0; i < 10; ++i)
            pp[i] = make_float4(accf[4 * i], accf[4 * i + 1],
                                accf[4 * i + 2], accf[4 * i + 3]);
    }
    __syncthreads();

    // ---- combine + finalize: thread q < 16 owns query qof+q ----
    if (t < 16) {
        const int g2 = t >> 2, qq = t & 3;
        float r[10];
#pragma unroll
        for (int j = 0; j < 10; ++j) {
            float s = 0.f;
#pragma unroll
            for (int w = 0; w < 4; ++w)
#pragma unroll
                for (int hb = 0; hb < 2; ++hb)
                    s += part[(((((w << 2) + g2) << 1) + hb) * 40) + qq * 10 + j];
            r[j] = s;
        }
        const float inv0 = 1.0f / r[0];
        const float inv1 = 1.0f / r[1];
        const float y[8] = {r[2] * inv0, r[3] * inv0, r[4] * inv0, r[5] * inv0,
                            r[6] * inv1, r[7] * inv1, r[8] * inv1, r[9] * inv1};
        float o[8];
        qrow(th, y, o);
        float4* op = (float4*)(out + ((size_t)(b * SEQ + qof + t)) * 8);
        op[0] = make_float4(o[0], o[1], o[2], o[3]);
        op[1] = make_float4(o[4], o[5], o[6], o[7]);
    }
}

extern "C" void kernel_launch(void* const* d_in, const int* in_sizes, int n_in,
                              void* d_out, int out_size, void* d_ws, size_t ws_size,
                              hipStream_t stream) {
    const float* x     = (const float*)d_in[0];
    const float* theta = (const float*)d_in[1];
    float* out         = (float*)d_out;
    mhaq_fused<<<dim3(1024), dim3(256), 0, stream>>>(x, theta, out);
}

// Round 4
// 66.406 us; speedup vs baseline: 1.3283x; 1.0569x over previous
//
#include <hip/hip_runtime.h>

#define SEQ 1024

typedef __attribute__((ext_vector_type(2))) float f2;

// h storage: row k = two 16B slots s=2k, 2k+1; physical slot P(s)=s^((s>>6)&7)
// (word addr 4*P). Bijective involution (bits 0..2 XORed by untouched bits 6..8).
// Access patterns (bank cluster = 4-bank group = P&7):
//  - inner key read: s = kh*1024 + m*64 + 2i -> cluster ((2i)&7)^(m&7); per
//    wave-read (i,kh fixed) the 16 m-lanes hit all 8 clusters 2x -> 2-way, free.
//  - stage-0 store: 64 consecutive rows/wave -> all 8 clusters 8-deep
//    (8-way within cluster but all clusters busy = 128B/clk, bandwidth-optimal).
//  - q-loads: 16-lane broadcast groups, 4 distinct slots/read.
static __device__ __forceinline__ int slot_addr(int s) {
    return (s ^ ((s >> 6) & 7)) << 2;
}

// Closed-form qlayer for one token row y[0..7]:
// angles a = {y0+t0, y1+t1, y2+y3+t2, t3, y4+t4, y5+t5, y6+t6, y7+t7}
// c_w = cos(a_w); out[0] = c1..c7, out[w] = c0..cw (w>=1).
static __device__ __forceinline__ void qrow(const float th[8], const float y[8], float o[8]) {
    float a[8];
    a[0] = y[0] + th[0];
    a[1] = y[1] + th[1];
    a[2] = y[2] + y[3] + th[2];
    a[3] = th[3];
    a[4] = y[4] + th[4];
    a[5] = y[5] + th[5];
    a[6] = y[6] + th[6];
    a[7] = y[7] + th[7];
    float c[8];
#pragma unroll
    for (int w = 0; w < 8; ++w) c[w] = __cosf(a[w]);
    o[1] = c[0] * c[1];
#pragma unroll
    for (int w = 2; w < 8; ++w) o[w] = o[w - 1] * c[w];
    float s = c[7];
#pragma unroll
    for (int w = 6; w >= 1; --w) s *= c[w];
    o[0] = s;
}

// Fused qlayer -> 2-head attention (dk=4) -> qlayer.
// v5 (clean occupancy test): 512 blocks (16 batches x 32 tiles of 32 q) --
// SAME total stage-0 work as R0 -- but 512 threads (8 waves)/block.
// LDS 42 KB (h 32 KB + partials 10 KB, no overlay) -> 2-3 blocks/CU =
// 16-24 waves/CU (4-6/SIMD, 2-3x R0). Packed f2 math (R0 form; R3 showed
// scalar costs +50% issue). Per thread: 2 q x 32 k. Live regs ~80 << 128 cap.
// Wave wv: qs=wv>>1 8-query set, kh=wv&1 512-key half; lane: g=2-query
// group, m=32-key chunk. Reduction: 2-step shfl_xor over m bits 0..1,
// survivors (m%4==0) dump 20 floats -> 128 rows x 20 words; 32 threads
// combine 8 rows each + finalize. One barrier fewer than R0.
__global__ __launch_bounds__(512, 4) void mhaq_fused(const float* __restrict__ x,
                                                     const float* __restrict__ theta,
                                                     float* __restrict__ out) {
    __shared__ __align__(16) float smem[8192 + 2560];
    float* const part = smem + 8192;

    const int b   = blockIdx.x >> 5;         // batch
    const int qof = (blockIdx.x & 31) << 5;  // first query of this block's 32
    const int t   = threadIdx.x;

    float th[8];
#pragma unroll
    for (int w = 0; w < 8; ++w) th[w] = theta[w];

    // ---- Stage 0: h[b] (1024 x 8) into LDS (2 rows/thread) ----
    const float4* xb = (const float4*)(x + (size_t)b * SEQ * 8);
    float4 va[2], vb[2];
#pragma unroll
    for (int r = 0; r < 2; ++r) {
        const int k = t + (r << 9);
        va[r] = xb[2 * k];
        vb[r] = xb[2 * k + 1];
    }
#pragma unroll
    for (int r = 0; r < 2; ++r) {
        const int k = t + (r << 9);
        const float y[8] = {va[r].x, va[r].y, va[r].z, va[r].w,
                            vb[r].x, vb[r].y, vb[r].z, vb[r].w};
        float o[8];
        qrow(th, y, o);
        *(float4*)&smem[slot_addr(2 * k)]     = make_float4(o[0], o[1], o[2], o[3]);
        *(float4*)&smem[slot_addr(2 * k + 1)] = make_float4(o[4], o[5], o[6], o[7]);
    }
    __syncthreads();

    // ---- Stage 2: attention inner loop ----
    const int lane = t & 63;
    const int wv   = t >> 6;      // wave 0..7
    const int qs   = wv >> 1;     // 8-query set 0..3
    const int kh   = wv & 1;      // key half 0..1 (512 keys)
    const int g    = lane >> 4;   // 2-query group 0..3
    const int m    = lane & 15;   // 32-key chunk 0..15
    const int q0   = qof + (qs << 3) + (g << 1);

    const float qscale = 0.5f * 1.44269504f;  // 1/sqrt(dk) * log2(e)
    f2 qv[2][4];
#pragma unroll
    for (int qq = 0; qq < 2; ++qq) {
        const float4 qa = *(const float4*)&smem[slot_addr(2 * (q0 + qq))];      // broadcast
        const float4 qb = *(const float4*)&smem[slot_addr(2 * (q0 + qq) + 1)];  // broadcast
        qv[qq][0] = f2{qa.x, qa.y} * qscale;
        qv[qq][1] = f2{qa.z, qa.w} * qscale;
        qv[qq][2] = f2{qb.x, qb.y} * qscale;
        qv[qq][3] = f2{qb.z, qb.w} * qscale;
    }

    float l0[2] = {0.f, 0.f};
    float l1[2] = {0.f, 0.f};
    f2 a01[2], a23[2], a45[2], a67[2];
#pragma unroll
    for (int qq = 0; qq < 2; ++qq) {
        a01[qq] = f2{0.f, 0.f};
        a23[qq] = f2{0.f, 0.f};
        a45[qq] = f2{0.f, 0.f};
        a67[qq] = f2{0.f, 0.f};
    }

    const int sbase = (kh << 10) + (m << 6);  // slot of this lane's first key
#pragma unroll 4
    for (int i = 0; i < 32; ++i) {
        const int s0 = sbase + (i << 1);
        const float4 k0 = *(const float4*)&smem[slot_addr(s0)];
        const float4 k1 = *(const float4*)&smem[slot_addr(s0 + 1)];
        const f2 k01 = {k0.x, k0.y}, k23 = {k0.z, k0.w};
        const f2 k45 = {k1.x, k1.y}, k67 = {k1.z, k1.w};
#pragma unroll
        for (int qq = 0; qq < 2; ++qq) {
            const f2 d0 = qv[qq][0] * k01 + qv[qq][1] * k23;
            const f2 d1 = qv[qq][2] * k45 + qv[qq][3] * k67;
            const float e0 = __builtin_amdgcn_exp2f(d0.x + d0.y);
            const float e1 = __builtin_amdgcn_exp2f(d1.x + d1.y);
            l0[qq] += e0;
            l1[qq] += e1;
            const f2 e0v = {e0, e0}, e1v = {e1, e1};
            a01[qq] += e0v * k01;
            a23[qq] += e0v * k23;
            a45[qq] += e1v * k45;
            a67[qq] += e1v * k67;
        }
    }

    // ---- 2-step shfl_xor over m bits 0..1 (reduces groups of 4 m-lanes) ----
    float buf[20];
#pragma unroll
    for (int qq = 0; qq < 2; ++qq) {
        buf[qq * 10 + 0] = l0[qq];
        buf[qq * 10 + 1] = l1[qq];
        buf[qq * 10 + 2] = a01[qq].x;
        buf[qq * 10 + 3] = a01[qq].y;
        buf[qq * 10 + 4] = a23[qq].x;
        buf[qq * 10 + 5] = a23[qq].y;
        buf[qq * 10 + 6] = a45[qq].x;
        buf[qq * 10 + 7] = a45[qq].y;
        buf[qq * 10 + 8] = a67[qq].x;
        buf[qq * 10 + 9] = a67[qq].y;
    }
#pragma unroll
    for (int j = 0; j < 20; ++j) {
        float v = buf[j];
        v += __shfl_xor(v, 1, 64);
        v += __shfl_xor(v, 2, 64);
        buf[j] = v;
    }

    // ---- dump: survivors m%4==0 -> 16 rows/wave, 128 rows x 20 words ----
    // float4 #ii at word 20*rid+4*ii -> cluster (5*rid+ii)&7; 16 consecutive
    // rid hit all 8 clusters 2x -> 2-way, free. (partials separate from h:
    // no overlay barrier needed between loop end and dump.)
    if ((m & 3) == 0) {
        const int rid = (wv << 4) + (g << 2) + (m >> 2);
        float4* pp = (float4*)&part[rid * 20];
#pragma unroll
        for (int ii = 0; ii < 5; ++ii) pp[ii] = ((const float4*)buf)[ii];
    }
    __syncthreads();

    // ---- combine + finalize: thread q < 32 owns query qof+q ----
    if (t < 32) {
        const int qs2 = t >> 3, g2 = (t >> 1) & 3, qq = t & 1;
        float r[10];
#pragma unroll
        for (int j = 0; j < 10; ++j) {
            float s = 0.f;
#pragma unroll
            for (int kh2 = 0; kh2 < 2; ++kh2)
#pragma unroll
                for (int mv = 0; mv < 4; ++mv)
                    s += part[((((qs2 << 1) + kh2) << 4) + (g2 << 2) + mv) * 20 + qq * 10 + j];
            r[j] = s;
        }
        const float inv0 = 1.0f / r[0];
        const float inv1 = 1.0f / r[1];
        const float y[8] = {r[2] * inv0, r[3] * inv0, r[4] * inv0, r[5] * inv0,
                            r[6] * inv1, r[7] * inv1, r[8] * inv1, r[9] * inv1};
        float o[8];
        qrow(th, y, o);
        float4* op = (float4*)(out + ((size_t)(b * SEQ + qof + t)) * 8);
        op[0] = make_float4(o[0], o[1], o[2], o[3]);
        op[1] = make_float4(o[4], o[5], o[6], o[7]);
    }
}

extern "C" void kernel_launch(void* const* d_in, const int* in_sizes, int n_in,
                              void* d_out, int out_size, void* d_ws, size_t ws_size,
                              hipStream_t stream) {
    const float* x     = (const float*)d_in[0];
    const float* theta = (const float*)d_in[1];
    float* out         = (float*)d_out;
    mhaq_fused<<<dim3(512), dim3(512), 0, stream>>>(x, theta, out);
}